// Round 3
// baseline (425.408 us; speedup 1.0000x reference)
//
#include <hip/hip_runtime.h>
#include <hip/hip_bf16.h>

#define THREADS 256
#define KW 40      // padded LDS row stride (shorts) for 32-k weight chunks
#define HP 136     // padded LDS row stride (shorts) for h rows

typedef float f32x4 __attribute__((ext_vector_type(4)));
typedef short s16x8 __attribute__((ext_vector_type(8)));

static __device__ __forceinline__ short f2b(float x) {
    return __builtin_bit_cast(short, __float2bfloat16(x));
}
static __device__ __forceinline__ float b2f(short u) {
    unsigned int v = ((unsigned int)(unsigned short)u) << 16;
    return __builtin_bit_cast(float, v);
}
static __device__ __forceinline__ void split8(const f32x4 a, const f32x4 b, s16x8& hi, s16x8& lo) {
    #pragma unroll
    for (int j = 0; j < 4; ++j) {
        short h0 = f2b(a[j]); hi[j]   = h0; lo[j]   = f2b(a[j] - b2f(h0));
        short h1 = f2b(b[j]); hi[j+4] = h1; lo[j+4] = f2b(b[j] - b2f(h1));
    }
}
static __device__ __forceinline__ s16x8 cvt8(const f32x4 a, const f32x4 b) {
    s16x8 r;
    r[0]=f2b(a[0]); r[1]=f2b(a[1]); r[2]=f2b(a[2]); r[3]=f2b(a[3]);
    r[4]=f2b(b[0]); r[5]=f2b(b[1]); r[6]=f2b(b[2]); r[7]=f2b(b[3]);
    return r;
}
static __device__ __forceinline__ float sigm(float x) { return 1.0f / (1.0f + __expf(-x)); }

#define MFMA16(A,B,C) __builtin_amdgcn_mfma_f32_16x16x32_bf16((A),(B),(C),0,0,0)

// ---- pre-pass: split Wf1/Wf2 into hi/lo bf16 (staging image layout) + W2 -> bf16 ----
// ws layout (shorts): [wv][cp][plane][row][k32]  = 2*32*2*128*32 = 524288 shorts (1 MB)
//                     then W2 bf16 [128][128]    = 16384 shorts (32 KB)
__global__ __launch_bounds__(256) void itemfusing_prep(
    const float* __restrict__ Wf1, const float* __restrict__ Wf2,
    const float* __restrict__ W2, short* __restrict__ wsp)
{
    const int t = blockIdx.x * 256 + threadIdx.x;
    if (t < 65536) {
        const int idx = t * 8;                 // short index
        const int k0 = idx & 31;
        const int r  = (idx >> 5) & 127;
        const int p  = (idx >> 12) & 1;
        const int cp = (idx >> 13) & 31;
        const int wv = idx >> 18;
        const float* src = (wv ? Wf2 : Wf1) + (size_t)r * 1024 + cp * 32 + k0;
        f32x4 a = *(const f32x4*)src, b = *(const f32x4*)(src + 4);
        s16x8 hi, lo; split8(a, b, hi, lo);
        *(s16x8*)(wsp + idx) = p ? lo : hi;
    } else {
        const int t2 = t - 65536;
        if (t2 < 2048) {
            const int idx = t2 * 8;
            const float* src = W2 + idx;
            *(s16x8*)(wsp + 524288 + idx) = cvt8(*(const f32x4*)src, *(const f32x4*)(src + 4));
        }
    }
}

template<bool PRE>
__global__ __launch_bounds__(THREADS, 3) void itemfusing_main(
    const float* __restrict__ inter, const float* __restrict__ intra,
    const float* __restrict__ Wf1, const float* __restrict__ bf1,
    const float* __restrict__ Wf2, const float* __restrict__ bf2,
    const float* __restrict__ W1,  const float* __restrict__ b1,
    const float* __restrict__ W2,  const float* __restrict__ b2,
    const float* __restrict__ qw,  const float* __restrict__ qb,
    const float* __restrict__ W3,  const float* __restrict__ b3,
    const short* __restrict__ wsp, const short* __restrict__ w2b,
    float* __restrict__ out)
{
    __shared__ union {
        short wbuf[2][2][128][KW];   // [buf][hi/lo][n][k]  : 40960 B
        short hbuf[2][32][HP];       // h rows for 2 sessions : 17408 B
    } u;
    __shared__ float vn  [2][128];   // 1024 B
    __shared__ float w1v [2][128];   // 1024 B
    __shared__ float sglp[2][2][128];// 2048 B   -> total 45056 B => 3 blocks/CU

    const int tid = threadIdx.x;
    const int l   = tid & 63;
    const int l15 = l & 15;
    const int kg  = l >> 4;
    const int w   = tid >> 6;     // 0..3
    const int s   = w >> 1;       // session slot in block (0..1)
    const int mt  = w & 1;        // m-tile within session (16 rows)
    const int sess = blockIdx.x * 2 + s;
    const int arow = sess * 32 + mt * 16 + l15;

    const float* aF1 = inter + (size_t)arow * 1024 + kg * 8;
    const float* aF2 = intra + (size_t)arow * 1024 + kg * 8;

    // staging decode
    const int sp = tid >> 7;          // plane (PRE)
    const int sr = tid & 127;         // row   (PRE)
    const int fr = tid >> 1;          // row   (!PRE)
    const int fk = (tid & 1) * 16;    // k-off (!PRE)
    const short* wsp_t = PRE ? (wsp + sp * 4096 + sr * 32) : nullptr;

    s16x8 wr0, wr1, wr2, wr3;         // PRE prefetch regs
    f32x4 fw0, fw1, fw2, fw3;         // !PRE prefetch regs

#define WLOAD(WV, CP) do {                                                                  \
    if constexpr (PRE) { const short* p_ = wsp_t + ((WV) * 32 + (CP)) * 8192;               \
        wr0 = *(const s16x8*)p_;        wr1 = *(const s16x8*)(p_ + 8);                      \
        wr2 = *(const s16x8*)(p_ + 16); wr3 = *(const s16x8*)(p_ + 24); }                   \
    else { const float* p_ = ((WV) ? Wf2 : Wf1) + (size_t)fr * 1024 + (CP) * 32 + fk;       \
        fw0 = *(const f32x4*)p_;        fw1 = *(const f32x4*)(p_ + 4);                      \
        fw2 = *(const f32x4*)(p_ + 8);  fw3 = *(const f32x4*)(p_ + 12); } } while (0)

#define WSTORE(BUF) do {                                                                    \
    if constexpr (PRE) { short* d_ = &u.wbuf[BUF][sp][sr][0];                               \
        *(s16x8*)d_ = wr0;        *(s16x8*)(d_ + 8) = wr1;                                  \
        *(s16x8*)(d_ + 16) = wr2; *(s16x8*)(d_ + 24) = wr3; }                               \
    else { s16x8 h0_, l0_, h1_, l1_;                                                        \
        split8(fw0, fw1, h0_, l0_); split8(fw2, fw3, h1_, l1_);                             \
        short* dh_ = &u.wbuf[BUF][0][fr][fk]; short* dl_ = &u.wbuf[BUF][1][fr][fk];         \
        *(s16x8*)dh_ = h0_; *(s16x8*)(dh_ + 8) = h1_;                                       \
        *(s16x8*)dl_ = l0_; *(s16x8*)(dl_ + 8) = l1_; } } while (0)

    f32x4 acc1[8], acc2[8];
    #pragma unroll
    for (int nt = 0; nt < 8; ++nt) {
        acc1[nt] = f32x4{0.f, 0.f, 0.f, 0.f};
        acc2[nt] = f32x4{0.f, 0.f, 0.f, 0.f};
    }

    // prologue: stage piece0 (Wf1,cp0) -> buf0; prefetch piece1 (Wf2,cp0); load A regs
    WLOAD(0, 0); WSTORE(0);
    WLOAD(1, 0);
    f32x4 raF1a = *(const f32x4*)aF1, raF1b = *(const f32x4*)(aF1 + 4);
    f32x4 raF2a = *(const f32x4*)aF2, raF2b = *(const f32x4*)(aF2 + 4);
    __syncthreads();

    // ---------------- phase 1: 32 cp-iterations, 2 regions each ----------------
    #pragma unroll 1
    for (int cp = 0; cp < 32; ++cp) {
        const bool more = (cp < 31);
        {   // EVEN region: acc1 <- (Wf1,cp) in buf0, A = raF1
            WSTORE(1);                       // stage (Wf2,cp) -> buf1
            if (more) WLOAD(0, cp + 1);      // prefetch (Wf1,cp+1)
            s16x8 ah, al; split8(raF1a, raF1b, ah, al);
            if (more) { const float* p = aF1 + (cp + 1) * 32;
                raF1a = *(const f32x4*)p; raF1b = *(const f32x4*)(p + 4); }
            #pragma unroll
            for (int nt = 0; nt < 8; ++nt) {
                s16x8 bh = *(const s16x8*)&u.wbuf[0][0][nt * 16 + l15][kg * 8];
                s16x8 bl = *(const s16x8*)&u.wbuf[0][1][nt * 16 + l15][kg * 8];
                acc1[nt] = MFMA16(ah, bh, acc1[nt]);
                acc1[nt] = MFMA16(al, bh, acc1[nt]);
                acc1[nt] = MFMA16(ah, bl, acc1[nt]);
            }
        }
        __syncthreads();
        {   // ODD region: acc2 <- (Wf2,cp) in buf1, A = raF2
            if (more) { WSTORE(0); WLOAD(1, cp + 1); }   // stage (Wf1,cp+1)->buf0, prefetch (Wf2,cp+1)
            s16x8 ah, al; split8(raF2a, raF2b, ah, al);
            if (more) { const float* p = aF2 + (cp + 1) * 32;
                raF2a = *(const f32x4*)p; raF2b = *(const f32x4*)(p + 4); }
            #pragma unroll
            for (int nt = 0; nt < 8; ++nt) {
                s16x8 bh = *(const s16x8*)&u.wbuf[1][0][nt * 16 + l15][kg * 8];
                s16x8 bl = *(const s16x8*)&u.wbuf[1][1][nt * 16 + l15][kg * 8];
                acc2[nt] = MFMA16(ah, bh, acc2[nt]);
                acc2[nt] = MFMA16(al, bh, acc2[nt]);
                acc2[nt] = MFMA16(ah, bl, acc2[nt]);
            }
        }
        __syncthreads();
    }

    // ---------------- phase 2: bias + gate -> h (fp32, in acc1) ----------------
    #pragma unroll
    for (int nt = 0; nt < 8; ++nt) {
        const int n = nt * 16 + l15;
        const float bb1 = bf1[n], bb2 = bf2[n];
        #pragma unroll
        for (int rj = 0; rj < 4; ++rj) {
            float x1 = acc1[nt][rj] + bb1;
            float x2 = acc2[nt][rj] + bb2;
            float g  = sigm(x1 + x2);
            acc1[nt][rj] = x2 + g * (x1 - x2);
        }
    }

    // v_n (session row 31 lives in wave mt=1, kg=3, rj=3)
    if (mt == 1 && kg == 3) {
        #pragma unroll
        for (int nt = 0; nt < 8; ++nt) vn[s][nt * 16 + l15] = acc1[nt][3];
    }
    __syncthreads();   // B1: vn visible; wbuf reads all done

    // ---------------- phase 3: w1v = W1 @ v_n + b1 (1 output/thread) ----------
    {
        const int n = mt * 64 + l;
        const float* w1r = W1 + (size_t)n * 128;
        float acc = b1[n];
        #pragma unroll
        for (int kk = 0; kk < 128; kk += 4) {
            f32x4 vv = *(const f32x4*)&vn[s][kk];
            f32x4 u0 = *(const f32x4*)(w1r + kk);
            #pragma unroll
            for (int j = 0; j < 4; ++j) acc += u0[j] * vv[j];
        }
        w1v[s][n] = acc;
    }
    // h rows -> LDS bf16 (own 16 rows)
    short (*hb)[HP] = u.hbuf[s];
    #pragma unroll
    for (int nt = 0; nt < 8; ++nt)
        #pragma unroll
        for (int rj = 0; rj < 4; ++rj)
            hb[mt * 16 + kg * 4 + rj][nt * 16 + l15] = f2b(acc1[nt][rj]);
    __syncthreads();   // B2: w1v + hbuf visible

    // ---------------- phase 4: w2h = h @ W2^T (MFMA, K=128, own 16 rows) ------
    f32x4 aw[8];
    #pragma unroll
    for (int nt = 0; nt < 8; ++nt) aw[nt] = f32x4{0.f, 0.f, 0.f, 0.f};
    #pragma unroll
    for (int ks = 0; ks < 4; ++ks) {
        const int kl = ks * 32 + kg * 8;
        s16x8 ah = *(const s16x8*)&hb[mt * 16 + l15][kl];
        #pragma unroll
        for (int nt = 0; nt < 8; ++nt) {
            s16x8 bw;
            if constexpr (PRE) {
                bw = *(const s16x8*)&w2b[(size_t)(nt * 16 + l15) * 128 + kl];
            } else {
                const float* wp = W2 + (size_t)(nt * 16 + l15) * 128 + kl;
                bw = cvt8(*(const f32x4*)wp, *(const f32x4*)(wp + 4));
            }
            aw[nt] = MFMA16(ah, bw, aw[nt]);
        }
    }

    // ---------------- phase 5: alpha rows (wave-local) -------------------------
    float prt[4] = {0.f, 0.f, 0.f, 0.f};
    #pragma unroll
    for (int nt = 0; nt < 8; ++nt) {
        const int n = nt * 16 + l15;
        const float qn = qw[n], wv_ = w1v[s][n], bb = b2[n];
        #pragma unroll
        for (int rj = 0; rj < 4; ++rj)
            prt[rj] += qn * sigm(wv_ + aw[nt][rj] + bb);
    }
    const float qbias = qb[0];
    #pragma unroll
    for (int rj = 0; rj < 4; ++rj) {
        float v = prt[rj];
        v += __shfl_xor(v, 1); v += __shfl_xor(v, 2);
        v += __shfl_xor(v, 4); v += __shfl_xor(v, 8);
        prt[rj] = v + qbias;          // alpha for row mt*16 + kg*4 + rj
    }

    // ---------------- phase 6: s_g partial over own 16 rows --------------------
    #pragma unroll
    for (int nt = 0; nt < 8; ++nt) {
        float sgv = 0.f;
        #pragma unroll
        for (int rj = 0; rj < 4; ++rj) sgv += prt[rj] * acc1[nt][rj];
        sgv += __shfl_xor(sgv, 16);
        sgv += __shfl_xor(sgv, 32);
        if (l < 16) sglp[s][mt][nt * 16 + l15] = sgv;
    }
    __syncthreads();   // B3: sglp visible

    // ---------------- phase 7: out = W3 @ [v_n ; s_g] + b3 ---------------------
    {
        const int n = mt * 64 + l;
        const float* w3r = W3 + (size_t)n * 256;
        float o = b3[n];
        #pragma unroll
        for (int kk = 0; kk < 128; kk += 4) {
            f32x4 vv = *(const f32x4*)&vn[s][kk];
            f32x4 s0 = *(const f32x4*)&sglp[s][0][kk];
            f32x4 s1 = *(const f32x4*)&sglp[s][1][kk];
            f32x4 a0 = *(const f32x4*)(w3r + kk);
            f32x4 c0 = *(const f32x4*)(w3r + 128 + kk);
            #pragma unroll
            for (int j = 0; j < 4; ++j)
                o += a0[j] * vv[j] + c0[j] * (s0[j] + s1[j]);
        }
        out[(size_t)sess * 128 + (mt * 64 + l)] = o;
    }
#undef WLOAD
#undef WSTORE
}

extern "C" void kernel_launch(void* const* d_in, const int* in_sizes, int n_in,
                              void* d_out, int out_size, void* d_ws, size_t ws_size,
                              hipStream_t stream) {
    (void)n_in; (void)out_size;
    const float* inter = (const float*)d_in[0];
    const float* intra = (const float*)d_in[1];
    const float* Wf1   = (const float*)d_in[3];
    const float* bf1   = (const float*)d_in[4];
    const float* Wf2   = (const float*)d_in[5];
    const float* bf2   = (const float*)d_in[6];
    const float* W1    = (const float*)d_in[7];
    const float* b1    = (const float*)d_in[8];
    const float* W2    = (const float*)d_in[9];
    const float* b2    = (const float*)d_in[10];
    const float* qw    = (const float*)d_in[11];
    const float* qb    = (const float*)d_in[12];
    const float* W3    = (const float*)d_in[13];
    const float* b3    = (const float*)d_in[14];
    float* out = (float*)d_out;

    const int nsess   = in_sizes[2];     // 4096
    const int nblocks = nsess / 2;       // 2048

    const size_t WS_NEED = (size_t)(524288 + 16384) * sizeof(short);
    if (d_ws != nullptr && ws_size >= WS_NEED) {
        short* wsp = (short*)d_ws;
        itemfusing_prep<<<264, 256, 0, stream>>>(Wf1, Wf2, W2, wsp);
        itemfusing_main<true><<<nblocks, THREADS, 0, stream>>>(
            inter, intra, Wf1, bf1, Wf2, bf2, W1, b1, W2, b2, qw, qb, W3, b3,
            wsp, wsp + 524288, out);
    } else {
        itemfusing_main<false><<<nblocks, THREADS, 0, stream>>>(
            inter, intra, Wf1, bf1, Wf2, bf2, W1, b1, W2, b2, qw, qb, W3, b3,
            nullptr, nullptr, out);
    }
}